// Round 3
// baseline (48.703 us; speedup 1.0000x reference)
//
#include <hip/hip_runtime.h>
#include <math.h>

#define D 128
#define BGRAPHS 256
// level 0: R=24 rows/graph; level 1: R=40 rows/graph
// ws layout (ushort elems): W bf16 planes, 4 matrices x (hi,lo) 16384 each:
//   Wh  hi@0      lo@16384
//   Wt  hi@32768  lo@49152
//   Whl hi@65536  lo@81920
//   Wtl hi@98304  lo@114688     total 131072 elems = 256 KB

typedef float f32x4 __attribute__((ext_vector_type(4)));
typedef short s16x8 __attribute__((ext_vector_type(8)));

__device__ __forceinline__ unsigned bf16h(float f) {
    unsigned u = __float_as_uint(f);
    return (u + 0x7fffu + ((u >> 16) & 1u)) >> 16;   // RNE
}
__device__ __forceinline__ float bf16tof(unsigned h) { return __uint_as_float(h << 16); }

__device__ __forceinline__ void split2x4(float4 a, float4 b, s16x8& h, s16x8& lo) {
    float f[8] = {a.x, a.y, a.z, a.w, b.x, b.y, b.z, b.w};
#pragma unroll
    for (int e = 0; e < 8; ++e) {
        unsigned hh = bf16h(f[e]);
        h[e] = (short)hh;
        lo[e] = (short)bf16h(f[e] - bf16tof(hh));
    }
}

// Convert the 4 W matrices (128x128 f32) to hi/lo bf16 planes in ws.
__global__ __launch_bounds__(256) void prep_w(
    const float* __restrict__ w0, const float* __restrict__ w1,
    const float* __restrict__ w2, const float* __restrict__ w3,
    unsigned short* __restrict__ ws)
{
    int t = blockIdx.x * 256 + threadIdx.x;          // 0..16383 float4s
    int m = t >> 12;
    int q = t & 4095;
    const float* src = (m == 0) ? w0 : (m == 1) ? w1 : (m == 2) ? w2 : w3;
    float4 va = *reinterpret_cast<const float4*>(src + q * 4);
    unsigned h0 = bf16h(va.x), h1 = bf16h(va.y), h2 = bf16h(va.z), h3 = bf16h(va.w);
    ushort4 hv = make_ushort4((unsigned short)h0, (unsigned short)h1,
                              (unsigned short)h2, (unsigned short)h3);
    ushort4 lv = make_ushort4((unsigned short)bf16h(va.x - bf16tof(h0)),
                              (unsigned short)bf16h(va.y - bf16tof(h1)),
                              (unsigned short)bf16h(va.z - bf16tof(h2)),
                              (unsigned short)bf16h(va.w - bf16tof(h3)));
    unsigned short* hp = ws + m * 32768;
    *reinterpret_cast<ushort4*>(hp + q * 4) = hv;
    *reinterpret_cast<ushort4*>(hp + 16384 + q * 4) = lv;
}

// Compute G (R x 256) = x @ [WA^T | WB^T] + [biasA | biasB] for one graph,
// store hi/lo bf16 into LDS planes with XOR swizzle (col ^= (row&7)<<3).
// Wave w handles output cols [w*64, w*64+64).
// MFMA rule (validated r1): mfma(P,Q,C): lane(lm,lq) reg r = dot(P_row[lq*4+r], Q_row[lm]),
// both fragments loaded row=lane&15, k=(lane>>4)*8+e.
template <int R, int TM>
__device__ __forceinline__ void compute_G(
    const float* __restrict__ xbase,
    const unsigned short* __restrict__ wAhi, const unsigned short* __restrict__ wAlo,
    const unsigned short* __restrict__ wBhi, const unsigned short* __restrict__ wBlo,
    const float* __restrict__ biasA, const float* __restrict__ biasB,
    unsigned short* Ghi, unsigned short* Glo,
    int w, int lm, int lq)
{
    const f32x4 zf = {0.f, 0.f, 0.f, 0.f};
    const s16x8 z8 = {0, 0, 0, 0, 0, 0, 0, 0};
    f32x4 acc[TM][4];
#pragma unroll
    for (int ti = 0; ti < TM; ++ti)
#pragma unroll
        for (int c = 0; c < 4; ++c) acc[ti][c] = zf;

#pragma unroll
    for (int ks = 0; ks < 4; ++ks) {
        const int k0 = ks * 32 + lq * 8;
        s16x8 qh[TM], ql[TM];
#pragma unroll
        for (int ti = 0; ti < TM; ++ti) {
            int i = ti * 16 + lm;
            bool vi = (i < R);
            int ic = vi ? i : (R - 1);
            const float* xr = xbase + ic * D + k0;
            float4 va = *reinterpret_cast<const float4*>(xr);
            float4 vb = *reinterpret_cast<const float4*>(xr + 4);
            s16x8 hv, lv;
            split2x4(va, vb, hv, lv);
            qh[ti] = vi ? hv : z8;
            ql[ti] = vi ? lv : z8;
        }
#pragma unroll
        for (int ctl = 0; ctl < 4; ++ctl) {
            const int n0 = (w * 4 + ctl) * 16;
            const unsigned short* pH;
            const unsigned short* pL;
            if (n0 < 128) {
                pH = wAhi + (n0 + lm) * 128 + k0;
                pL = wAlo + (n0 + lm) * 128 + k0;
            } else {
                pH = wBhi + (n0 - 128 + lm) * 128 + k0;
                pL = wBlo + (n0 - 128 + lm) * 128 + k0;
            }
            s16x8 Ph = *reinterpret_cast<const s16x8*>(pH);
            s16x8 Pl = *reinterpret_cast<const s16x8*>(pL);
#pragma unroll
            for (int ti = 0; ti < TM; ++ti) {
                f32x4 c = acc[ti][ctl];
                c = __builtin_amdgcn_mfma_f32_16x16x32_bf16(Ph, qh[ti], c, 0, 0, 0);
                c = __builtin_amdgcn_mfma_f32_16x16x32_bf16(Ph, ql[ti], c, 0, 0, 0);
                c = __builtin_amdgcn_mfma_f32_16x16x32_bf16(Pl, qh[ti], c, 0, 0, 0);
                acc[ti][ctl] = c;
            }
        }
    }

    // epilogue: lane holds G[i = ti*16+lm][n = (w*4+ctl)*16 + lq*4 + r]
#pragma unroll
    for (int ctl = 0; ctl < 4; ++ctl) {
        const int n0 = (w * 4 + ctl) * 16;
        const int nc = n0 + lq * 4;
        const float* bp = (n0 < 128) ? (biasA + nc) : (biasB + nc - 128);
        float4 b4 = *reinterpret_cast<const float4*>(bp);
#pragma unroll
        for (int ti = 0; ti < TM; ++ti) {
            int i = ti * 16 + lm;
            bool vi = (i < R);
            if (vi) {
                float y0 = acc[ti][ctl][0] + b4.x;
                float y1 = acc[ti][ctl][1] + b4.y;
                float y2 = acc[ti][ctl][2] + b4.z;
                float y3 = acc[ti][ctl][3] + b4.w;
                unsigned h0 = bf16h(y0), h1 = bf16h(y1), h2 = bf16h(y2), h3 = bf16h(y3);
                ushort4 hv = make_ushort4((unsigned short)h0, (unsigned short)h1,
                                          (unsigned short)h2, (unsigned short)h3);
                ushort4 lv = make_ushort4((unsigned short)bf16h(y0 - bf16tof(h0)),
                                          (unsigned short)bf16h(y1 - bf16tof(h1)),
                                          (unsigned short)bf16h(y2 - bf16tof(h2)),
                                          (unsigned short)bf16h(y3 - bf16tof(h3)));
                int off = i * 256 + (nc ^ ((i & 7) << 3));
                *reinterpret_cast<ushort4*>(&Ghi[off]) = hv;
                *reinterpret_cast<ushort4*>(&Glo[off]) = lv;
            }
        }
    }
}

template <int LEVEL>
__device__ __forceinline__ void fused_body(
    int g, const float* __restrict__ xh, const float* __restrict__ xt,
    const unsigned short* __restrict__ wsu,
    const float* __restrict__ biasH, const float* __restrict__ biasT,
    float* __restrict__ osh, float* __restrict__ ost,
    unsigned short* Gh_hi, unsigned short* Gh_lo,
    unsigned short* Gt_hi, unsigned short* Gt_lo,
    float* colpart, float* bh_s, float* pt_s, float* ph_s)
{
    constexpr int R = (LEVEL == 0) ? 24 : 40;
    constexpr int TM = (LEVEL == 0) ? 2 : 3;
    constexpr float invR = 1.f / (float)R;

    const int tid = threadIdx.x;
    const int w = tid >> 6, l = tid & 63;
    const int lm = l & 15, lq = l >> 4;
    const int base = g * R;

    const unsigned short* WHhi = wsu + (LEVEL ? 65536 : 0);
    const unsigned short* WHlo = WHhi + 16384;
    const unsigned short* WThi = wsu + (LEVEL ? 98304 : 32768);
    const unsigned short* WTlo = WThi + 16384;

    // G_h = xh @ [Wh^T | Wt^T] + [bh | bt];  G_t = xt @ [Wt^T | Wh^T] + [bt | bh]
    compute_G<R, TM>(xh + base * D, WHhi, WHlo, WThi, WTlo, biasH, biasT,
                     Gh_hi, Gh_lo, w, lm, lq);
    compute_G<R, TM>(xt + base * D, WThi, WTlo, WHhi, WHlo, biasT, biasH,
                     Gt_hi, Gt_lo, w, lm, lq);
    __syncthreads();

    // alpha = tanh(G_h @ G_t^T), distributed: wave w owns i-tile ti=w.
    // mfma(P=G_h frag, Q=G_t frag): i = w*16+lq*4+r, j = tj*16+lm.
    float cs[3] = {0.f, 0.f, 0.f};
    if (w < TM) {
        const s16x8 z8 = {0, 0, 0, 0, 0, 0, 0, 0};
        const f32x4 zf = {0.f, 0.f, 0.f, 0.f};
        f32x4 acc2[TM];
#pragma unroll
        for (int tj = 0; tj < TM; ++tj) acc2[tj] = zf;

        const int ri = w * 16 + lm;
        const bool vi = (ri < R);
        const int ric = vi ? ri : (R - 1);
#pragma unroll
        for (int ksa = 0; ksa < 8; ++ksa) {
            const int k0 = ksa * 32 + lq * 8;
            const int offA = ric * 256 + (k0 ^ ((ric & 7) << 3));
            s16x8 Ah = *reinterpret_cast<const s16x8*>(&Gh_hi[offA]);
            s16x8 Al = *reinterpret_cast<const s16x8*>(&Gh_lo[offA]);
            Ah = vi ? Ah : z8;
            Al = vi ? Al : z8;
#pragma unroll
            for (int tj = 0; tj < TM; ++tj) {
                int rj = tj * 16 + lm;
                bool vj = (rj < R);
                int rjc = vj ? rj : (R - 1);
                int offB = rjc * 256 + (k0 ^ ((rjc & 7) << 3));
                s16x8 Bh = *reinterpret_cast<const s16x8*>(&Gt_hi[offB]);
                s16x8 Bl = *reinterpret_cast<const s16x8*>(&Gt_lo[offB]);
                Bh = vj ? Bh : z8;
                Bl = vj ? Bl : z8;
                f32x4 c = acc2[tj];
                c = __builtin_amdgcn_mfma_f32_16x16x32_bf16(Ah, Bh, c, 0, 0, 0);
                c = __builtin_amdgcn_mfma_f32_16x16x32_bf16(Ah, Bl, c, 0, 0, 0);
                c = __builtin_amdgcn_mfma_f32_16x16x32_bf16(Al, Bh, c, 0, 0, 0);
                acc2[tj] = c;
            }
        }

        float at[TM][4];
#pragma unroll
        for (int tj = 0; tj < TM; ++tj)
#pragma unroll
            for (int r = 0; r < 4; ++r) at[tj][r] = tanhf(acc2[tj][r]);

        // row sums over j -> bh_s[i] (i = w*16 + lq*4 + r)
#pragma unroll
        for (int r = 0; r < 4; ++r) {
            float s = 0.f;
#pragma unroll
            for (int tj = 0; tj < TM; ++tj) s += at[tj][r];
            s += __shfl_xor(s, 1, 64);
            s += __shfl_xor(s, 2, 64);
            s += __shfl_xor(s, 4, 64);
            s += __shfl_xor(s, 8, 64);
            if (lm == 0) bh_s[w * 16 + lq * 4 + r] = s;
        }
        // col partial sums over i-tile -> cs[tj] (j = tj*16+lm)
#pragma unroll
        for (int tj = 0; tj < TM; ++tj) {
            float s = 0.f;
#pragma unroll
            for (int r = 0; r < 4; ++r) s += at[tj][r];
            s += __shfl_xor(s, 16, 64);
            s += __shfl_xor(s, 32, 64);
            cs[tj] = s;
        }
    }
#pragma unroll
    for (int tj = 0; tj < 3; ++tj)
        if (lq == 0) colpart[w * 48 + tj * 16 + lm] = (tj < TM) ? cs[tj] : 0.f;
    __syncthreads();

    // softmaxes: wave0 -> p_t (col sums / R), wave1 -> p_h (row sums / R)
    if (w == 0) {
        float v = (l < 48) ? (colpart[l] + colpart[48 + l] + colpart[96 + l] + colpart[144 + l]) : 0.f;
        float val = (l < R) ? v * invR : -INFINITY;
        float m = val;
        for (int o = 32; o; o >>= 1) m = fmaxf(m, __shfl_xor(m, o, 64));
        float e = (l < R) ? expf(val - m) : 0.f;
        float s = e;
        for (int o = 32; o; o >>= 1) s += __shfl_xor(s, o, 64);
        if (l < R) pt_s[l] = e / s;
    } else if (w == 1) {
        float val = (l < R) ? bh_s[l] * invR : -INFINITY;
        float m = val;
        for (int o = 32; o; o >>= 1) m = fmaxf(m, __shfl_xor(m, o, 64));
        float e = (l < R) ? expf(val - m) : 0.f;
        float s = e;
        for (int o = 32; o; o >>= 1) s += __shfl_xor(s, o, 64);
        if (l < R) ph_s[l] = e / s;
    }
    __syncthreads();

    // outputs: threads 0..127 -> s_t col c; 128..255 -> s_h col c
    if (tid < 128) {
        int c = tid;
        float a = 0.f;
        for (int j = 0; j < R; ++j) a += pt_s[j] * xt[(base + j) * D + c];
        ost[g * D + c] = a;
    } else {
        int c = tid - 128;
        float a = 0.f;
        for (int i = 0; i < R; ++i) a += ph_s[i] * xh[(base + i) * D + c];
        osh[g * D + c] = a;
    }
}

__global__ __launch_bounds__(256) void fused_kernel(
    const float* __restrict__ xnh, const float* __restrict__ xnt,
    const float* __restrict__ xlh, const float* __restrict__ xlt,
    const unsigned short* __restrict__ wsu,
    const float* __restrict__ bh, const float* __restrict__ bt,
    const float* __restrict__ bhl, const float* __restrict__ btl,
    float* __restrict__ out)
{
    __shared__ unsigned short Gh_hi[10240], Gh_lo[10240], Gt_hi[10240], Gt_lo[10240];
    __shared__ float colpart[192], bh_s[48], pt_s[48], ph_s[48];

    int idx = blockIdx.x;
    if (idx < 256)
        fused_body<0>(idx, xnh, xnt, wsu, bh, bt, out + 0, out + 32768,
                      Gh_hi, Gh_lo, Gt_hi, Gt_lo, colpart, bh_s, pt_s, ph_s);
    else
        fused_body<1>(idx - 256, xlh, xlt, wsu, bhl, btl, out + 65536, out + 98304,
                      Gh_hi, Gh_lo, Gt_hi, Gt_lo, colpart, bh_s, pt_s, ph_s);
}

extern "C" void kernel_launch(void* const* d_in, const int* in_sizes, int n_in,
                              void* d_out, int out_size, void* d_ws, size_t ws_size,
                              hipStream_t stream) {
    const float* xnh   = (const float*)d_in[0];
    const float* xnt   = (const float*)d_in[1];
    const float* xlh   = (const float*)d_in[2];
    const float* xlt   = (const float*)d_in[3];
    const float* Wh_w  = (const float*)d_in[4];
    const float* Wh_b  = (const float*)d_in[5];
    const float* Wt_w  = (const float*)d_in[6];
    const float* Wt_b  = (const float*)d_in[7];
    const float* Whl_w = (const float*)d_in[8];
    const float* Whl_b = (const float*)d_in[9];
    const float* Wtl_w = (const float*)d_in[10];
    const float* Wtl_b = (const float*)d_in[11];

    unsigned short* ws = (unsigned short*)d_ws;
    float* out = (float*)d_out;

    prep_w<<<64, 256, 0, stream>>>(Wh_w, Wt_w, Whl_w, Wtl_w, ws);
    fused_kernel<<<512, 256, 0, stream>>>(xnh, xnt, xlh, xlt, ws,
                                          Wh_b, Wt_b, Whl_b, Wtl_b, out);
}

// Round 4
// 33.092 us; speedup vs baseline: 1.4717x; 1.4717x over previous
//
#include <hip/hip_runtime.h>
#include <math.h>

#define D 128
// level 0: R=24 rows/graph (nodes); level 1: R=40 rows/graph (line graph)
// out layout (floats): s_h@0, s_t@32768, s_h_line@65536, s_t_line@98304

typedef float f32x4 __attribute__((ext_vector_type(4)));
typedef _Float16 f16x8 __attribute__((ext_vector_type(8)));

union PK4 { _Float16 h[4]; ushort4 v; };

__device__ __forceinline__ f16x8 cvt8(float4 a, float4 b) {
    f16x8 r;
    r[0] = (_Float16)a.x; r[1] = (_Float16)a.y; r[2] = (_Float16)a.z; r[3] = (_Float16)a.w;
    r[4] = (_Float16)b.x; r[5] = (_Float16)b.y; r[6] = (_Float16)b.z; r[7] = (_Float16)b.w;
    return r;
}

// G (R x 256) = x @ [WA^T | WB^T] + [biasA | biasB], fp16, stored to LDS with
// XOR swizzle (half-col ^= (row&7)<<3  == byte ^= (row&7)<<4).
// MFMA rule (validated r1/r2): mfma(P,Q): lane(lm,lq) reg r = dot(P_row[lq*4+r], Q_row[lm]);
// fragments loaded row = lane&15, k = (lane>>4)*8 + e.
template <int R, int TM>
__device__ __forceinline__ void compute_G(
    const float* __restrict__ xbase,
    const float* __restrict__ WA, const float* __restrict__ WB,
    const float* __restrict__ biasA, const float* __restrict__ biasB,
    _Float16* G, int w, int lm, int lq)
{
    const f16x8 z8 = {0, 0, 0, 0, 0, 0, 0, 0};
    f32x4 acc[TM][4];
#pragma unroll
    for (int ti = 0; ti < TM; ++ti)
#pragma unroll
        for (int c = 0; c < 4; ++c) acc[ti][c] = (f32x4){0.f, 0.f, 0.f, 0.f};

#pragma unroll
    for (int ks = 0; ks < 4; ++ks) {
        const int k0 = ks * 32 + lq * 8;
        f16x8 q[TM];
#pragma unroll
        for (int ti = 0; ti < TM; ++ti) {
            int i = ti * 16 + lm;
            bool vi = (i < R);
            const float* xr = xbase + (vi ? i : (R - 1)) * D + k0;
            float4 va = *reinterpret_cast<const float4*>(xr);
            float4 vb = *reinterpret_cast<const float4*>(xr + 4);
            f16x8 v = cvt8(va, vb);
            q[ti] = vi ? v : z8;
        }
#pragma unroll
        for (int ctl = 0; ctl < 4; ++ctl) {
            const int n0 = (w * 4 + ctl) * 16;
            const float* wp = (n0 < 128) ? (WA + (n0 + lm) * D + k0)
                                         : (WB + (n0 - 128 + lm) * D + k0);
            float4 wa = *reinterpret_cast<const float4*>(wp);
            float4 wb = *reinterpret_cast<const float4*>(wp + 4);
            f16x8 P = cvt8(wa, wb);
#pragma unroll
            for (int ti = 0; ti < TM; ++ti)
                acc[ti][ctl] = __builtin_amdgcn_mfma_f32_16x16x32_f16(P, q[ti], acc[ti][ctl], 0, 0, 0);
        }
    }

    // epilogue: lane holds G[i = ti*16+lm][n = (w*4+ctl)*16 + lq*4 + r]
#pragma unroll
    for (int ctl = 0; ctl < 4; ++ctl) {
        const int n0 = (w * 4 + ctl) * 16;
        const int nc = n0 + lq * 4;
        const float* bp = (n0 < 128) ? (biasA + nc) : (biasB + nc - 128);
        float4 b4 = *reinterpret_cast<const float4*>(bp);
#pragma unroll
        for (int ti = 0; ti < TM; ++ti) {
            int i = ti * 16 + lm;
            if (i < R) {
                PK4 pk;
                pk.h[0] = (_Float16)(acc[ti][ctl][0] + b4.x);
                pk.h[1] = (_Float16)(acc[ti][ctl][1] + b4.y);
                pk.h[2] = (_Float16)(acc[ti][ctl][2] + b4.z);
                pk.h[3] = (_Float16)(acc[ti][ctl][3] + b4.w);
                int off = i * 256 + (nc ^ ((i & 7) << 3));
                *reinterpret_cast<ushort4*>(&G[off]) = pk.v;
            }
        }
    }
}

template <int LEVEL>
__device__ __forceinline__ void fused_body(
    int g, const float* __restrict__ xh, const float* __restrict__ xt,
    const float* __restrict__ WH, const float* __restrict__ WT,
    const float* __restrict__ biasH, const float* __restrict__ biasT,
    float* __restrict__ osh, float* __restrict__ ost,
    _Float16* Gh, _Float16* Gt,
    float* colpart, float* bh_s, float* pt_s, float* ph_s)
{
    constexpr int R = (LEVEL == 0) ? 24 : 40;
    constexpr int TM = (LEVEL == 0) ? 2 : 3;
    constexpr float invR = 1.f / (float)R;

    const int tid = threadIdx.x;
    const int w = tid >> 6, l = tid & 63;
    const int lm = l & 15, lq = l >> 4;
    const int base = g * R;

    // G_h = xh @ [Wh^T | Wt^T] + [bh | bt];  G_t = xt @ [Wt^T | Wh^T] + [bt | bh]
    compute_G<R, TM>(xh + base * D, WH, WT, biasH, biasT, Gh, w, lm, lq);
    compute_G<R, TM>(xt + base * D, WT, WH, biasT, biasH, Gt, w, lm, lq);
    __syncthreads();

    // alpha = tanh(G_h @ G_t^T); wave w owns i-tile w. i = w*16+lq*4+r, j = tj*16+lm.
    float cs[3] = {0.f, 0.f, 0.f};
    if (w < TM) {
        const f16x8 z8 = {0, 0, 0, 0, 0, 0, 0, 0};
        f32x4 acc2[TM];
#pragma unroll
        for (int tj = 0; tj < TM; ++tj) acc2[tj] = (f32x4){0.f, 0.f, 0.f, 0.f};

        const int ri = w * 16 + lm;
        const bool vi = (ri < R);
        const int ric = vi ? ri : (R - 1);
#pragma unroll
        for (int ksa = 0; ksa < 8; ++ksa) {
            const int k0 = ksa * 32 + lq * 8;
            const int offA = ric * 256 + (k0 ^ ((ric & 7) << 3));
            f16x8 Ah = *reinterpret_cast<const f16x8*>(&Gh[offA]);
            Ah = vi ? Ah : z8;
#pragma unroll
            for (int tj = 0; tj < TM; ++tj) {
                int rj = tj * 16 + lm;
                bool vj = (rj < R);
                int rjc = vj ? rj : (R - 1);
                int offB = rjc * 256 + (k0 ^ ((rjc & 7) << 3));
                f16x8 Bh = *reinterpret_cast<const f16x8*>(&Gt[offB]);
                Bh = vj ? Bh : z8;
                acc2[tj] = __builtin_amdgcn_mfma_f32_16x16x32_f16(Ah, Bh, acc2[tj], 0, 0, 0);
            }
        }

        float at[TM][4];
#pragma unroll
        for (int tj = 0; tj < TM; ++tj)
#pragma unroll
            for (int r = 0; r < 4; ++r) at[tj][r] = tanhf(acc2[tj][r]);

        // row sums over j -> bh_s[i] (i = w*16 + lq*4 + r); padded cols are tanh(0)=0
#pragma unroll
        for (int r = 0; r < 4; ++r) {
            float s = 0.f;
#pragma unroll
            for (int tj = 0; tj < TM; ++tj) s += at[tj][r];
            s += __shfl_xor(s, 1, 64);
            s += __shfl_xor(s, 2, 64);
            s += __shfl_xor(s, 4, 64);
            s += __shfl_xor(s, 8, 64);
            if (lm == 0) bh_s[w * 16 + lq * 4 + r] = s;
        }
        // col partial sums over this i-tile -> cs[tj] (j = tj*16+lm)
#pragma unroll
        for (int tj = 0; tj < TM; ++tj) {
            float s = 0.f;
#pragma unroll
            for (int r = 0; r < 4; ++r) s += at[tj][r];
            s += __shfl_xor(s, 16, 64);
            s += __shfl_xor(s, 32, 64);
            cs[tj] = s;
        }
    }
#pragma unroll
    for (int tj = 0; tj < 3; ++tj)
        if (lq == 0) colpart[w * 48 + tj * 16 + lm] = (tj < 3 && tj < TM) ? cs[tj] : 0.f;
    __syncthreads();

    // softmaxes: wave0 -> p_t (col sums / R), wave1 -> p_h (row sums / R)
    if (w == 0) {
        float v = (l < 48) ? (colpart[l] + colpart[48 + l] + colpart[96 + l] + colpart[144 + l]) : 0.f;
        float val = (l < R) ? v * invR : -INFINITY;
        float m = val;
        for (int o = 32; o; o >>= 1) m = fmaxf(m, __shfl_xor(m, o, 64));
        float e = (l < R) ? expf(val - m) : 0.f;
        float s = e;
        for (int o = 32; o; o >>= 1) s += __shfl_xor(s, o, 64);
        if (l < R) pt_s[l] = e / s;
    } else if (w == 1) {
        float val = (l < R) ? bh_s[l] * invR : -INFINITY;
        float m = val;
        for (int o = 32; o; o >>= 1) m = fmaxf(m, __shfl_xor(m, o, 64));
        float e = (l < R) ? expf(val - m) : 0.f;
        float s = e;
        for (int o = 32; o; o >>= 1) s += __shfl_xor(s, o, 64);
        if (l < R) ph_s[l] = e / s;
    }
    __syncthreads();

    // outputs: threads 0..127 -> s_t col c; 128..255 -> s_h col c
    if (tid < 128) {
        int c = tid;
        float a = 0.f;
        for (int j = 0; j < R; ++j) a += pt_s[j] * xt[(base + j) * D + c];
        ost[g * D + c] = a;
    } else {
        int c = tid - 128;
        float a = 0.f;
        for (int i = 0; i < R; ++i) a += ph_s[i] * xh[(base + i) * D + c];
        osh[g * D + c] = a;
    }
}

__global__ __launch_bounds__(256, 3) void fused_kernel(
    const float* __restrict__ xnh, const float* __restrict__ xnt,
    const float* __restrict__ xlh, const float* __restrict__ xlt,
    const float* __restrict__ Wh, const float* __restrict__ bh,
    const float* __restrict__ Wt, const float* __restrict__ bt,
    const float* __restrict__ Whl, const float* __restrict__ bhl,
    const float* __restrict__ Wtl, const float* __restrict__ btl,
    float* __restrict__ out)
{
    __shared__ __align__(16) _Float16 Gh[10240];
    __shared__ __align__(16) _Float16 Gt[10240];
    __shared__ float colpart[192], bh_s[48], pt_s[48], ph_s[48];

    int idx = blockIdx.x;
    if (idx < 256)
        fused_body<0>(idx, xnh, xnt, Wh, Wt, bh, bt, out + 0, out + 32768,
                      Gh, Gt, colpart, bh_s, pt_s, ph_s);
    else
        fused_body<1>(idx - 256, xlh, xlt, Whl, Wtl, bhl, btl, out + 65536, out + 98304,
                      Gh, Gt, colpart, bh_s, pt_s, ph_s);
}

extern "C" void kernel_launch(void* const* d_in, const int* in_sizes, int n_in,
                              void* d_out, int out_size, void* d_ws, size_t ws_size,
                              hipStream_t stream) {
    const float* xnh   = (const float*)d_in[0];
    const float* xnt   = (const float*)d_in[1];
    const float* xlh   = (const float*)d_in[2];
    const float* xlt   = (const float*)d_in[3];
    const float* Wh_w  = (const float*)d_in[4];
    const float* Wh_b  = (const float*)d_in[5];
    const float* Wt_w  = (const float*)d_in[6];
    const float* Wt_b  = (const float*)d_in[7];
    const float* Whl_w = (const float*)d_in[8];
    const float* Whl_b = (const float*)d_in[9];
    const float* Wtl_w = (const float*)d_in[10];
    const float* Wtl_b = (const float*)d_in[11];

    float* out = (float*)d_out;

    fused_kernel<<<512, 256, 0, stream>>>(xnh, xnt, xlh, xlt,
                                          Wh_w, Wh_b, Wt_w, Wt_b,
                                          Whl_w, Whl_b, Wtl_w, Wtl_b, out);
}